// Round 1
// baseline (2628.801 us; speedup 1.0000x reference)
//
#include <hip/hip_runtime.h>
#include <math.h>

// Problem constants
#define B_    512
#define W_    4
#define KD_   64
#define NC_   32
#define D_    256
#define NN_   16
#define NH_   8
#define AD_   32
#define HOPS_ 4
#define DH_   32
#define DFF_  1024
#define P_    2560
#define BW_   2048   // B*W

#define INV_SQRT_DH 0.17677669529663687f  // 1/sqrt(32)

// ---------------- block-wide sum over 256 threads ----------------
__device__ __forceinline__ float block_sum256(float v, float* red) {
#pragma unroll
  for (int off = 32; off > 0; off >>= 1) v += __shfl_xor(v, off, 64);
  int wid = threadIdx.x >> 6;
  if ((threadIdx.x & 63) == 0) red[wid] = v;
  __syncthreads();
  float s = red[0] + red[1] + red[2] + red[3];
  __syncthreads();
  return s;
}

__device__ __forceinline__ float gelu_tanh(float v) {
  float u = 0.7978845608028654f * (v + 0.044715f * v * v * v);
  return 0.5f * v * (1.0f + tanhf(u));
}

// ---------------- encode writers + queries -> h, node ----------------
__global__ __launch_bounds__(256) void encode_kernel(
    const float* __restrict__ query_keys, const float* __restrict__ writer_keys,
    const float* __restrict__ kpw, const float* __restrict__ kpb,
    const float* __restrict__ ce, const float* __restrict__ re,
    const float* __restrict__ sne, const float* __restrict__ ilg,
    const float* __restrict__ ilb, const int* __restrict__ qsn,
    const int* __restrict__ wl, const int* __restrict__ wsn,
    float* __restrict__ h, int* __restrict__ node) {
  int p = blockIdx.x, t = threadIdx.x;
  __shared__ float fk[KD_];
  __shared__ float red[4];
  const float* key;
  int lab = -1, sn, role;
  if (p < BW_) { key = writer_keys + (size_t)p * KD_; lab = wl[p]; sn = wsn[p]; role = 0; }
  else { int b = p - BW_; key = query_keys + (size_t)b * KD_; sn = qsn[b]; role = 1; }
  if (t < KD_) fk[t] = key[t];
  __syncthreads();

  float acc = kpb[t] + sne[sn * D_ + t] + re[role * D_ + t];
  if (lab >= 0) acc += ce[lab * D_ + t];
#pragma unroll 8
  for (int i = 0; i < KD_; i++) acc += fk[i] * kpw[i * D_ + t];

  float mean = block_sum256(acc, red) * (1.0f / D_);
  float d = acc - mean;
  float var = block_sum256(d * d, red) * (1.0f / D_);
  float xn = d * (1.0f / sqrtf(var + 1e-5f));

  float sw = 0.0f;
  if (t < KD_) sw = fk[t];
  else if (lab >= 0 && t < KD_ + NC_) sw = (t - KD_ == lab) ? 1.0f : 0.0f;

  h[(size_t)p * D_ + t] = xn * ilg[t] + ilb[t] + sw;
  if (t == 0) node[p] = sn;
}

// ---------------- group packets by node ----------------
__global__ __launch_bounds__(256) void sort_kernel(const int* __restrict__ node,
                                                   int* __restrict__ order,
                                                   int* __restrict__ offs,
                                                   int* __restrict__ cnts) {
  __shared__ int c[NN_], o[NN_], cur[NN_];
  int t = threadIdx.x;
  if (t < NN_) c[t] = 0;
  __syncthreads();
  for (int p = t; p < P_; p += 256) atomicAdd(&c[node[p]], 1);
  __syncthreads();
  if (t == 0) {
    int s = 0;
    for (int n = 0; n < NN_; n++) { o[n] = s; cur[n] = s; s += c[n]; }
  }
  __syncthreads();
  if (t < NN_) { cnts[t] = c[t]; offs[t] = o[t]; }
  for (int p = t; p < P_; p += 256) {
    int r = atomicAdd(&cur[node[p]], 1);
    order[r] = p;
  }
}

// ---------------- LN with per-node affine ----------------
__global__ __launch_bounds__(256) void ln_affine(const float* __restrict__ h,
                                                 const float* __restrict__ g,
                                                 const float* __restrict__ b,
                                                 const int* __restrict__ node,
                                                 float* __restrict__ x) {
  int p = blockIdx.x, t = threadIdx.x;
  __shared__ float red[4];
  int n = node[p];
  float v = h[(size_t)p * D_ + t];
  float mean = block_sum256(v, red) * (1.0f / D_);
  float d = v - mean;
  float var = block_sum256(d * d, red) * (1.0f / D_);
  float xn = d * (1.0f / sqrtf(var + 1e-5f));
  x[(size_t)p * D_ + t] = xn * g[n * D_ + t] + b[n * D_ + t];
}

// ---------------- grouped (per-node or dense) linear ----------------
// out[p, jbase:jbase+256] = act( x[p,:] @ W[n] + bias[n] )   (+= when RESID)
template <int DIN, int DOUT, int ACT, int RESID, int PER_NODE>
__global__ __launch_bounds__(256) void glin(const float* __restrict__ x,
                                            const float* __restrict__ W,
                                            const float* __restrict__ bias,
                                            float* __restrict__ out,
                                            const int* __restrict__ order,
                                            const int* __restrict__ offs,
                                            const int* __restrict__ cnts) {
  constexpr int KC = 32, TP = 32;
  int n = PER_NODE ? blockIdx.z : 0;
  int m = PER_NODE ? cnts[n] : P_;
  int t0 = blockIdx.x * TP;
  if (t0 >= m) return;
  int base = PER_NODE ? offs[n] : 0;
  int jbase = blockIdx.y * 256;

  __shared__ float ws[KC * 256];
  __shared__ float xs[KC * TP];  // transposed: xs[i*TP + tp]
  __shared__ int pid[TP];

  int tid = threadIdx.x;
  if (tid < TP) {
    int idx = t0 + tid;
    pid[tid] = (idx < m) ? (PER_NODE ? order[base + idx] : idx) : -1;
  }
  __syncthreads();

  int tj = tid & 63;       // 64 column-threads, 4 consecutive cols each
  int p0 = (tid >> 6) * 8; // 4 packet-groups of 8
  float acc[8][4];
#pragma unroll
  for (int k = 0; k < 8; k++)
#pragma unroll
    for (int c = 0; c < 4; c++) acc[k][c] = 0.0f;

  const float* Wn = W + (size_t)n * DIN * DOUT;

  for (int kc = 0; kc < DIN; kc += KC) {
#pragma unroll 4
    for (int i = 0; i < KC; i++)
      ws[i * 256 + tid] = Wn[(size_t)(kc + i) * DOUT + jbase + tid];
#pragma unroll
    for (int idx = tid; idx < KC * TP; idx += 256) {
      int i = idx / TP, tp = idx % TP;
      int pp = pid[tp];
      xs[idx] = (pp >= 0) ? x[(size_t)pp * DIN + kc + i] : 0.0f;
    }
    __syncthreads();
#pragma unroll 8
    for (int i = 0; i < KC; i++) {
      float4 bv = *(const float4*)&ws[i * 256 + tj * 4];
      float4 a0 = *(const float4*)&xs[i * TP + p0];
      float4 a1 = *(const float4*)&xs[i * TP + p0 + 4];
      float av[8] = {a0.x, a0.y, a0.z, a0.w, a1.x, a1.y, a1.z, a1.w};
#pragma unroll
      for (int k = 0; k < 8; k++) {
        acc[k][0] += av[k] * bv.x;
        acc[k][1] += av[k] * bv.y;
        acc[k][2] += av[k] * bv.z;
        acc[k][3] += av[k] * bv.w;
      }
    }
    __syncthreads();
  }

  float4 bb = *(const float4*)&bias[n * DOUT + jbase + tj * 4];
#pragma unroll
  for (int k = 0; k < 8; k++) {
    int pp = pid[p0 + k];
    if (pp < 0) continue;
    float4 r;
    r.x = acc[k][0] + bb.x;
    r.y = acc[k][1] + bb.y;
    r.z = acc[k][2] + bb.z;
    r.w = acc[k][3] + bb.w;
    if (ACT == 1) {
      r.x = gelu_tanh(r.x); r.y = gelu_tanh(r.y);
      r.z = gelu_tanh(r.z); r.w = gelu_tanh(r.w);
    }
    float* op = &out[(size_t)pp * DOUT + jbase + tj * 4];
    if (RESID) {
      float4 old = *(const float4*)op;
      r.x += old.x; r.y += old.y; r.z += old.z; r.w += old.w;
    }
    *(float4*)op = r;
  }
}

// ---------------- same-node attention (online softmax per group) ----------------
__global__ __launch_bounds__(256) void attn_kernel(const float* __restrict__ qkv,
                                                   const int* __restrict__ node,
                                                   const int* __restrict__ order,
                                                   const int* __restrict__ offs,
                                                   const int* __restrict__ cnts,
                                                   float* __restrict__ ao) {
  int p = blockIdx.x, tid = threadIdx.x;  // tid = head*32 + dh
  int n = node[p];
  int base = offs[n], m = cnts[n];
  float q = qkv[(size_t)p * 768 + tid] * INV_SQRT_DH;
  float mx = -INFINITY, l = 0.0f, o = 0.0f;
  for (int it = 0; it < m; ++it) {
    int kp = order[base + it];
    float kv = qkv[(size_t)kp * 768 + 256 + tid];
    float vv = qkv[(size_t)kp * 768 + 512 + tid];
    float s = q * kv;
#pragma unroll
    for (int off = 16; off > 0; off >>= 1) s += __shfl_xor(s, off, 32);
    float nmx = fmaxf(mx, s);
    float al = __expf(mx - nmx);  // 0 on first iter (mx=-inf)
    float pe = __expf(s - nmx);
    l = l * al + pe;
    o = o * al + pe * vv;
    mx = nmx;
  }
  ao[(size_t)p * D_ + tid] = o / l;
}

// ---------------- routing: dir scores -> argmax node; h += delta*sigmoid(mag) ----
__global__ __launch_bounds__(256) void route_kernel(float* __restrict__ h,
                                                    const float* __restrict__ dir_w,
                                                    const float* __restrict__ dir_b,
                                                    const float* __restrict__ at,
                                                    const float* __restrict__ mag_w,
                                                    const float* __restrict__ mag_b,
                                                    const float* __restrict__ delta,
                                                    int* __restrict__ node) {
  int p = blockIdx.x, t = threadIdx.x;
  __shared__ float hs[D_];
  __shared__ float dpart[8][AD_];
  __shared__ float dirs[AD_];
  __shared__ float scs[NN_];
  __shared__ float red[4];
  float hv = h[(size_t)p * D_ + t];
  hs[t] = hv;
  __syncthreads();

  // direction[:AD] only (the rest is never used by the reference)
  int j = t & 31, seg = t >> 5;
  float part = 0.0f;
#pragma unroll 8
  for (int i = 0; i < 32; i++) {
    int ii = seg * 32 + i;
    part += hs[ii] * dir_w[ii * D_ + j];
  }
  dpart[seg][j] = part;
  __syncthreads();
  if (t < AD_) {
    float s = dir_b[t];
#pragma unroll
    for (int g = 0; g < 8; g++) s += dpart[g][t];
    dirs[t] = s;
  }
  __syncthreads();
  if (t < NN_) {
    float s = 0.0f;
#pragma unroll
    for (int a = 0; a < AD_; a++) s += dirs[a] * at[t * AD_ + a];
    scs[t] = s;
  }
  __syncthreads();
  if (t == 0) {
    float best = scs[0];
    int arg = 0;
    for (int nn = 1; nn < NN_; nn++)
      if (scs[nn] > best) { best = scs[nn]; arg = nn; }  // first-max like jnp.argmax
    node[p] = arg;
  }
  // gated delta
  float mag = block_sum256(hv * mag_w[t], red) + mag_b[0];
  float sig = 1.0f / (1.0f + __expf(-mag));
  h[(size_t)p * D_ + t] = hv + delta[(size_t)p * D_ + t] * sig;
}

// ---------------- final logits ----------------
__global__ __launch_bounds__(256) void out_kernel(const float* __restrict__ h,
                                                  const float* __restrict__ ow,
                                                  const float* __restrict__ ob,
                                                  float* __restrict__ out) {
  int p = blockIdx.x, t = threadIdx.x;
  __shared__ float hs[D_];
  __shared__ float part[8][NC_];
  hs[t] = h[(size_t)p * D_ + t];
  __syncthreads();
  int j = t & 31, seg = t >> 5;
  float s = 0.0f;
#pragma unroll 8
  for (int i = 0; i < 32; i++) {
    int ii = seg * 32 + i;
    s += hs[ii] * ow[ii * NC_ + j];
  }
  part[seg][j] = s;
  __syncthreads();
  if (t < NC_) {
    float r = ob[t];
#pragma unroll
    for (int g = 0; g < 8; g++) r += part[g][t];
    out[(size_t)p * NC_ + t] = r;
  }
}

extern "C" void kernel_launch(void* const* d_in, const int* in_sizes, int n_in,
                              void* d_out, int out_size, void* d_ws, size_t ws_size,
                              hipStream_t stream) {
  (void)in_sizes; (void)n_in; (void)out_size; (void)ws_size;
  const float* query_keys       = (const float*)d_in[0];
  const float* writer_keys      = (const float*)d_in[1];
  const float* key_proj_w       = (const float*)d_in[2];
  const float* key_proj_b       = (const float*)d_in[3];
  const float* class_embed      = (const float*)d_in[4];
  const float* role_embed       = (const float*)d_in[5];
  const float* start_node_embed = (const float*)d_in[6];
  const float* input_ln_g       = (const float*)d_in[7];
  const float* input_ln_b       = (const float*)d_in[8];
  const float* ln1_g            = (const float*)d_in[9];
  const float* ln1_b            = (const float*)d_in[10];
  const float* wqkv             = (const float*)d_in[11];
  const float* bqkv             = (const float*)d_in[12];
  const float* wo               = (const float*)d_in[13];
  const float* bo               = (const float*)d_in[14];
  const float* ln2_g            = (const float*)d_in[15];
  const float* ln2_b            = (const float*)d_in[16];
  const float* w_fc1            = (const float*)d_in[17];
  const float* b_fc1            = (const float*)d_in[18];
  const float* w_fc2            = (const float*)d_in[19];
  const float* b_fc2            = (const float*)d_in[20];
  const float* delta_w          = (const float*)d_in[21];
  const float* delta_b          = (const float*)d_in[22];
  const float* dir_w            = (const float*)d_in[23];
  const float* dir_b            = (const float*)d_in[24];
  const float* mag_w            = (const float*)d_in[25];
  const float* mag_b            = (const float*)d_in[26];
  const float* out_w            = (const float*)d_in[27];
  const float* out_b            = (const float*)d_in[28];
  const float* address_table    = (const float*)d_in[29];
  const int* query_start_nodes  = (const int*)d_in[30];
  const int* writer_labels      = (const int*)d_in[31];
  const int* writer_start_nodes = (const int*)d_in[32];

  uintptr_t basep = (uintptr_t)d_ws;
  auto carve = [&](size_t bytes) {
    basep = (basep + 255) & ~(uintptr_t)255;
    void* r = (void*)basep;
    basep += bytes;
    return r;
  };
  float* h    = (float*)carve((size_t)P_ * D_ * 4);
  float* x    = (float*)carve((size_t)P_ * D_ * 4);   // reused: x / ao / x2 / delta
  float* qkvb = (float*)carve((size_t)P_ * 3 * D_ * 4);
  float* ff   = (float*)carve((size_t)P_ * DFF_ * 4);
  int* node   = (int*)carve(P_ * 4);
  int* order  = (int*)carve(P_ * 4);
  int* offs   = (int*)carve(NN_ * 4);
  int* cnts   = (int*)carve(NN_ * 4);

  const int GX = P_ / 32;  // 80 packet-tiles

  encode_kernel<<<P_, 256, 0, stream>>>(query_keys, writer_keys, key_proj_w, key_proj_b,
                                        class_embed, role_embed, start_node_embed,
                                        input_ln_g, input_ln_b, query_start_nodes,
                                        writer_labels, writer_start_nodes, h, node);

  for (int hop = 0; hop < HOPS_; ++hop) {
    sort_kernel<<<1, 256, 0, stream>>>(node, order, offs, cnts);
    ln_affine<<<P_, 256, 0, stream>>>(h, ln1_g, ln1_b, node, x);
    glin<256, 768, 0, 0, 1><<<dim3(GX, 3, NN_), 256, 0, stream>>>(x, wqkv, bqkv, qkvb,
                                                                  order, offs, cnts);
    attn_kernel<<<P_, 256, 0, stream>>>(qkvb, node, order, offs, cnts, x /*ao*/);
    glin<256, 256, 0, 1, 1><<<dim3(GX, 1, NN_), 256, 0, stream>>>(x, wo, bo, h,
                                                                  order, offs, cnts);
    ln_affine<<<P_, 256, 0, stream>>>(h, ln2_g, ln2_b, node, x);
    glin<256, 1024, 1, 0, 1><<<dim3(GX, 4, NN_), 256, 0, stream>>>(x, w_fc1, b_fc1, ff,
                                                                   order, offs, cnts);
    glin<1024, 256, 0, 1, 1><<<dim3(GX, 1, NN_), 256, 0, stream>>>(ff, w_fc2, b_fc2, h,
                                                                   order, offs, cnts);
    glin<256, 256, 0, 0, 0><<<dim3(GX, 1, 1), 256, 0, stream>>>(h, delta_w, delta_b,
                                                                x /*delta*/, nullptr,
                                                                nullptr, nullptr);
    route_kernel<<<P_, 256, 0, stream>>>(h, dir_w, dir_b, address_table, mag_w, mag_b,
                                         x, node);
  }

  out_kernel<<<P_, 256, 0, stream>>>(h, out_w, out_b, (float*)d_out);
}

// Round 2
// 2031.258 us; speedup vs baseline: 1.2942x; 1.2942x over previous
//
#include <hip/hip_runtime.h>
#include <math.h>

// Problem constants
#define B_    512
#define W_    4
#define KD_   64
#define NC_   32
#define D_    256
#define NN_   16
#define NH_   8
#define AD_   32
#define HOPS_ 4
#define DH_   32
#define DFF_  1024
#define P_    2560
#define BW_   2048   // B*W

#define INV_SQRT_DH 0.17677669529663687f  // 1/sqrt(32)

// ---------------- block-wide sum over 256 threads ----------------
__device__ __forceinline__ float block_sum256(float v, float* red) {
#pragma unroll
  for (int off = 32; off > 0; off >>= 1) v += __shfl_xor(v, off, 64);
  int wid = threadIdx.x >> 6;
  if ((threadIdx.x & 63) == 0) red[wid] = v;
  __syncthreads();
  float s = red[0] + red[1] + red[2] + red[3];
  __syncthreads();
  return s;
}

__device__ __forceinline__ float gelu_tanh(float v) {
  float u = 0.7978845608028654f * (v + 0.044715f * v * v * v);
  return 0.5f * v * (1.0f + tanhf(u));
}

// ---------------- encode writers + queries -> h, node ----------------
__global__ __launch_bounds__(256) void encode_kernel(
    const float* __restrict__ query_keys, const float* __restrict__ writer_keys,
    const float* __restrict__ kpw, const float* __restrict__ kpb,
    const float* __restrict__ ce, const float* __restrict__ re,
    const float* __restrict__ sne, const float* __restrict__ ilg,
    const float* __restrict__ ilb, const int* __restrict__ qsn,
    const int* __restrict__ wl, const int* __restrict__ wsn,
    float* __restrict__ h, int* __restrict__ node) {
  int p = blockIdx.x, t = threadIdx.x;
  __shared__ float fk[KD_];
  __shared__ float red[4];
  const float* key;
  int lab = -1, sn, role;
  if (p < BW_) { key = writer_keys + (size_t)p * KD_; lab = wl[p]; sn = wsn[p]; role = 0; }
  else { int b = p - BW_; key = query_keys + (size_t)b * KD_; sn = qsn[b]; role = 1; }
  if (t < KD_) fk[t] = key[t];
  __syncthreads();

  float acc = kpb[t] + sne[sn * D_ + t] + re[role * D_ + t];
  if (lab >= 0) acc += ce[lab * D_ + t];
#pragma unroll 8
  for (int i = 0; i < KD_; i++) acc += fk[i] * kpw[i * D_ + t];

  float mean = block_sum256(acc, red) * (1.0f / D_);
  float d = acc - mean;
  float var = block_sum256(d * d, red) * (1.0f / D_);
  float xn = d * (1.0f / sqrtf(var + 1e-5f));

  float sw = 0.0f;
  if (t < KD_) sw = fk[t];
  else if (lab >= 0 && t < KD_ + NC_) sw = (t - KD_ == lab) ? 1.0f : 0.0f;

  h[(size_t)p * D_ + t] = xn * ilg[t] + ilb[t] + sw;
  if (t == 0) node[p] = sn;
}

// ---------------- group packets by node ----------------
__global__ __launch_bounds__(256) void sort_kernel(const int* __restrict__ node,
                                                   int* __restrict__ order,
                                                   int* __restrict__ offs,
                                                   int* __restrict__ cnts) {
  __shared__ int c[NN_], o[NN_], cur[NN_];
  int t = threadIdx.x;
  if (t < NN_) c[t] = 0;
  __syncthreads();
  for (int p = t; p < P_; p += 256) atomicAdd(&c[node[p]], 1);
  __syncthreads();
  if (t == 0) {
    int s = 0;
    for (int n = 0; n < NN_; n++) { o[n] = s; cur[n] = s; s += c[n]; }
  }
  __syncthreads();
  if (t < NN_) { cnts[t] = c[t]; offs[t] = o[t]; }
  for (int p = t; p < P_; p += 256) {
    int r = atomicAdd(&cur[node[p]], 1);
    order[r] = p;
  }
}

// ---------------- LN with per-node affine ----------------
__global__ __launch_bounds__(256) void ln_affine(const float* __restrict__ h,
                                                 const float* __restrict__ g,
                                                 const float* __restrict__ b,
                                                 const int* __restrict__ node,
                                                 float* __restrict__ x) {
  int p = blockIdx.x, t = threadIdx.x;
  __shared__ float red[4];
  int n = node[p];
  float v = h[(size_t)p * D_ + t];
  float mean = block_sum256(v, red) * (1.0f / D_);
  float d = v - mean;
  float var = block_sum256(d * d, red) * (1.0f / D_);
  float xn = d * (1.0f / sqrtf(var + 1e-5f));
  x[(size_t)p * D_ + t] = xn * g[n * D_ + t] + b[n * D_ + t];
}

// ---------------- grouped (per-node or dense) linear ----------------
// out[p, jbase:jbase+256] = act( x[p,:] @ W[n] + bias[n] )   (+= when RESID)
template <int DIN, int DOUT, int ACT, int RESID, int PER_NODE>
__global__ __launch_bounds__(256) void glin(const float* __restrict__ x,
                                            const float* __restrict__ W,
                                            const float* __restrict__ bias,
                                            float* __restrict__ out,
                                            const int* __restrict__ order,
                                            const int* __restrict__ offs,
                                            const int* __restrict__ cnts) {
  constexpr int KC = 32, TP = 32;
  int n = PER_NODE ? blockIdx.z : 0;
  int m = PER_NODE ? cnts[n] : P_;
  int t0 = blockIdx.x * TP;
  if (t0 >= m) return;
  int base = PER_NODE ? offs[n] : 0;
  int jbase = blockIdx.y * 256;

  __shared__ float ws[KC * 256];
  __shared__ float xs[KC * TP];  // transposed: xs[i*TP + tp]
  __shared__ int pid[TP];

  int tid = threadIdx.x;
  if (tid < TP) {
    int idx = t0 + tid;
    pid[tid] = (idx < m) ? (PER_NODE ? order[base + idx] : idx) : -1;
  }
  __syncthreads();

  int tj = tid & 63;       // 64 column-threads, 4 consecutive cols each
  int p0 = (tid >> 6) * 8; // 4 packet-groups of 8
  float acc[8][4];
#pragma unroll
  for (int k = 0; k < 8; k++)
#pragma unroll
    for (int c = 0; c < 4; c++) acc[k][c] = 0.0f;

  const float* Wn = W + (size_t)n * DIN * DOUT;

  for (int kc = 0; kc < DIN; kc += KC) {
#pragma unroll 4
    for (int i = 0; i < KC; i++)
      ws[i * 256 + tid] = Wn[(size_t)(kc + i) * DOUT + jbase + tid];
#pragma unroll
    for (int idx = tid; idx < KC * TP; idx += 256) {
      int i = idx / TP, tp = idx % TP;
      int pp = pid[tp];
      xs[idx] = (pp >= 0) ? x[(size_t)pp * DIN + kc + i] : 0.0f;
    }
    __syncthreads();
#pragma unroll 8
    for (int i = 0; i < KC; i++) {
      float4 bv = *(const float4*)&ws[i * 256 + tj * 4];
      float4 a0 = *(const float4*)&xs[i * TP + p0];
      float4 a1 = *(const float4*)&xs[i * TP + p0 + 4];
      float av[8] = {a0.x, a0.y, a0.z, a0.w, a1.x, a1.y, a1.z, a1.w};
#pragma unroll
      for (int k = 0; k < 8; k++) {
        acc[k][0] += av[k] * bv.x;
        acc[k][1] += av[k] * bv.y;
        acc[k][2] += av[k] * bv.z;
        acc[k][3] += av[k] * bv.w;
      }
    }
    __syncthreads();
  }

  float4 bb = *(const float4*)&bias[n * DOUT + jbase + tj * 4];
#pragma unroll
  for (int k = 0; k < 8; k++) {
    int pp = pid[p0 + k];
    if (pp < 0) continue;
    float4 r;
    r.x = acc[k][0] + bb.x;
    r.y = acc[k][1] + bb.y;
    r.z = acc[k][2] + bb.z;
    r.w = acc[k][3] + bb.w;
    if (ACT == 1) {
      r.x = gelu_tanh(r.x); r.y = gelu_tanh(r.y);
      r.z = gelu_tanh(r.z); r.w = gelu_tanh(r.w);
    }
    float* op = &out[(size_t)pp * DOUT + jbase + tj * 4];
    if (RESID) {
      float4 old = *(const float4*)op;
      r.x += old.x; r.y += old.y; r.z += old.z; r.w += old.w;
    }
    *(float4*)op = r;
  }
}

// ---------------- same-node attention, flash-style over sorted order --------
// grid (P/32, NH). Block handles 32 sorted q-rows for one head.
// Groups are contiguous in sorted order, so the same-node mask is a range
// test on the sorted key index. Online softmax per row (8 lanes/row).
#define ATS 36  // padded LDS stride (floats): multiple of 4 (float4 align), !=32 (banks)
__global__ __launch_bounds__(256) void attn_kernel(const float* __restrict__ qkv,
                                                   const int* __restrict__ node,
                                                   const int* __restrict__ order,
                                                   const int* __restrict__ offs,
                                                   const int* __restrict__ cnts,
                                                   float* __restrict__ ao) {
  __shared__ float qs[32 * ATS];   // Q row-major [r][d]
  __shared__ float kts[32 * ATS];  // K transposed [d][j]
  __shared__ float vs[32 * ATS];   // V row-major [j][d]
  __shared__ float ps[32 * ATS];   // P row-major [r][j] (wave-coherent use)
  __shared__ int prow[32], glo[32], ghi[32];

  int t = threadIdx.x;
  int r = t >> 3;          // my q-row (and my staging key-row)
  int j4 = (t & 7) * 4;    // my 4 score-cols == my 4 output dims
  int r0 = blockIdx.x * 32;
  int hd = blockIdx.y;

  if (t < 32) {
    int sr = r0 + t;
    int pp = order[sr];
    prow[t] = pp;
    int n = node[pp];
    glo[t] = offs[n];
    ghi[t] = offs[n] + cnts[n];
  }
  __syncthreads();

  {  // load Q tile (wave-coherent with its consumers: row r lives in 8 lanes of one wave)
    const float* qp = &qkv[(size_t)prow[r] * 768 + hd * 32 + j4];
    float4 q4 = *(const float4*)qp;
    q4.x *= INV_SQRT_DH; q4.y *= INV_SQRT_DH; q4.z *= INV_SQRT_DH; q4.w *= INV_SQRT_DH;
    *(float4*)&qs[r * ATS + j4] = q4;
  }

  int lo = glo[0];          // sorted ascending => row 0 has min group start
  int hi = ghi[31];         // row 31 has max group end
  int myglo = glo[r], myghi = ghi[r];

  float4 o4 = {0.f, 0.f, 0.f, 0.f};
  float mrow = -1e30f, lrow = 0.f;

  for (int kt = lo; kt < hi; kt += 32) {
    // stage: this thread loads key-row (kt+r), dims j4..j4+3
    int sj = kt + r;
    float4 k4 = {0.f, 0.f, 0.f, 0.f}, v4 = {0.f, 0.f, 0.f, 0.f};
    if (sj < hi) {
      const float* kp = &qkv[(size_t)order[sj] * 768 + 256 + hd * 32 + j4];
      k4 = *(const float4*)kp;
      v4 = *(const float4*)(kp + 256);
    }
    __syncthreads();  // previous tile's kts/vs reads complete
    kts[(j4 + 0) * ATS + r] = k4.x;
    kts[(j4 + 1) * ATS + r] = k4.y;
    kts[(j4 + 2) * ATS + r] = k4.z;
    kts[(j4 + 3) * ATS + r] = k4.w;
    *(float4*)&vs[r * ATS + j4] = v4;
    __syncthreads();

    // scores: 4 cols per thread, dot over 32 dims
    float s0 = 0.f, s1 = 0.f, s2 = 0.f, s3 = 0.f;
#pragma unroll 8
    for (int d = 0; d < 32; d++) {
      float qv = qs[r * ATS + d];                     // broadcast within row-group
      float4 kv = *(const float4*)&kts[d * ATS + j4]; // conflict-free (stride 36)
      s0 += qv * kv.x; s1 += qv * kv.y; s2 += qv * kv.z; s3 += qv * kv.w;
    }
    // same-node mask via sorted range
    int c0 = kt + j4;
    if (c0 + 0 < myglo || c0 + 0 >= myghi) s0 = -1e30f;
    if (c0 + 1 < myglo || c0 + 1 >= myghi) s1 = -1e30f;
    if (c0 + 2 < myglo || c0 + 2 >= myghi) s2 = -1e30f;
    if (c0 + 3 < myglo || c0 + 3 >= myghi) s3 = -1e30f;

    // online softmax (per row across its 8 lanes)
    float mx = fmaxf(fmaxf(s0, s1), fmaxf(s2, s3));
#pragma unroll
    for (int off = 4; off > 0; off >>= 1) mx = fmaxf(mx, __shfl_xor(mx, off, 8));
    float mnew = fmaxf(mrow, mx);
    float alpha = __expf(mrow - mnew);  // exp(0)=1 harmless pre-first-valid (zeroed later)
    float p0 = __expf(s0 - mnew), p1 = __expf(s1 - mnew);
    float p2 = __expf(s2 - mnew), p3 = __expf(s3 - mnew);
    float ls = p0 + p1 + p2 + p3;
#pragma unroll
    for (int off = 4; off > 0; off >>= 1) ls += __shfl_xor(ls, off, 8);
    lrow = lrow * alpha + ls;
    mrow = mnew;
    o4.x *= alpha; o4.y *= alpha; o4.z *= alpha; o4.w *= alpha;

    // P -> LDS (row written & read by the same 8 lanes' wave: no barrier needed)
    *(float4*)&ps[r * ATS + j4] = make_float4(p0, p1, p2, p3);
#pragma unroll 8
    for (int j = 0; j < 32; j++) {
      float pj = ps[r * ATS + j];
      float4 vv = *(const float4*)&vs[j * ATS + j4];
      o4.x += pj * vv.x; o4.y += pj * vv.y; o4.z += pj * vv.z; o4.w += pj * vv.w;
    }
  }

  float inv = 1.f / lrow;
  o4.x *= inv; o4.y *= inv; o4.z *= inv; o4.w *= inv;
  *(float4*)&ao[(size_t)prow[r] * D_ + hd * 32 + j4] = o4;
}

// ---------------- routing: dir scores -> argmax node; h += delta*sigmoid(mag) ----
__global__ __launch_bounds__(256) void route_kernel(float* __restrict__ h,
                                                    const float* __restrict__ dir_w,
                                                    const float* __restrict__ dir_b,
                                                    const float* __restrict__ at,
                                                    const float* __restrict__ mag_w,
                                                    const float* __restrict__ mag_b,
                                                    const float* __restrict__ delta,
                                                    int* __restrict__ node) {
  int p = blockIdx.x, t = threadIdx.x;
  __shared__ float hs[D_];
  __shared__ float dpart[8][AD_];
  __shared__ float dirs[AD_];
  __shared__ float scs[NN_];
  __shared__ float red[4];
  float hv = h[(size_t)p * D_ + t];
  hs[t] = hv;
  __syncthreads();

  // direction[:AD] only (the rest is never used by the reference)
  int j = t & 31, seg = t >> 5;
  float part = 0.0f;
#pragma unroll 8
  for (int i = 0; i < 32; i++) {
    int ii = seg * 32 + i;
    part += hs[ii] * dir_w[ii * D_ + j];
  }
  dpart[seg][j] = part;
  __syncthreads();
  if (t < AD_) {
    float s = dir_b[t];
#pragma unroll
    for (int g = 0; g < 8; g++) s += dpart[g][t];
    dirs[t] = s;
  }
  __syncthreads();
  if (t < NN_) {
    float s = 0.0f;
#pragma unroll
    for (int a = 0; a < AD_; a++) s += dirs[a] * at[t * AD_ + a];
    scs[t] = s;
  }
  __syncthreads();
  if (t == 0) {
    float best = scs[0];
    int arg = 0;
    for (int nn = 1; nn < NN_; nn++)
      if (scs[nn] > best) { best = scs[nn]; arg = nn; }  // first-max like jnp.argmax
    node[p] = arg;
  }
  // gated delta
  float mag = block_sum256(hv * mag_w[t], red) + mag_b[0];
  float sig = 1.0f / (1.0f + __expf(-mag));
  h[(size_t)p * D_ + t] = hv + delta[(size_t)p * D_ + t] * sig;
}

// ---------------- final logits ----------------
__global__ __launch_bounds__(256) void out_kernel(const float* __restrict__ h,
                                                  const float* __restrict__ ow,
                                                  const float* __restrict__ ob,
                                                  float* __restrict__ out) {
  int p = blockIdx.x, t = threadIdx.x;
  __shared__ float hs[D_];
  __shared__ float part[8][NC_];
  hs[t] = h[(size_t)p * D_ + t];
  __syncthreads();
  int j = t & 31, seg = t >> 5;
  float s = 0.0f;
#pragma unroll 8
  for (int i = 0; i < 32; i++) {
    int ii = seg * 32 + i;
    s += hs[ii] * ow[ii * NC_ + j];
  }
  part[seg][j] = s;
  __syncthreads();
  if (t < NC_) {
    float r = ob[t];
#pragma unroll
    for (int g = 0; g < 8; g++) r += part[g][t];
    out[(size_t)p * NC_ + t] = r;
  }
}

extern "C" void kernel_launch(void* const* d_in, const int* in_sizes, int n_in,
                              void* d_out, int out_size, void* d_ws, size_t ws_size,
                              hipStream_t stream) {
  (void)in_sizes; (void)n_in; (void)out_size; (void)ws_size;
  const float* query_keys       = (const float*)d_in[0];
  const float* writer_keys      = (const float*)d_in[1];
  const float* key_proj_w       = (const float*)d_in[2];
  const float* key_proj_b       = (const float*)d_in[3];
  const float* class_embed      = (const float*)d_in[4];
  const float* role_embed       = (const float*)d_in[5];
  const float* start_node_embed = (const float*)d_in[6];
  const float* input_ln_g       = (const float*)d_in[7];
  const float* input_ln_b       = (const float*)d_in[8];
  const float* ln1_g            = (const float*)d_in[9];
  const float* ln1_b            = (const float*)d_in[10];
  const float* wqkv             = (const float*)d_in[11];
  const float* bqkv             = (const float*)d_in[12];
  const float* wo               = (const float*)d_in[13];
  const float* bo               = (const float*)d_in[14];
  const float* ln2_g            = (const float*)d_in[15];
  const float* ln2_b            = (const float*)d_in[16];
  const float* w_fc1            = (const float*)d_in[17];
  const float* b_fc1            = (const float*)d_in[18];
  const float* w_fc2            = (const float*)d_in[19];
  const float* b_fc2            = (const float*)d_in[20];
  const float* delta_w          = (const float*)d_in[21];
  const float* delta_b          = (const float*)d_in[22];
  const float* dir_w            = (const float*)d_in[23];
  const float* dir_b            = (const float*)d_in[24];
  const float* mag_w            = (const float*)d_in[25];
  const float* mag_b            = (const float*)d_in[26];
  const float* out_w            = (const float*)d_in[27];
  const float* out_b            = (const float*)d_in[28];
  const float* address_table    = (const float*)d_in[29];
  const int* query_start_nodes  = (const int*)d_in[30];
  const int* writer_labels      = (const int*)d_in[31];
  const int* writer_start_nodes = (const int*)d_in[32];

  uintptr_t basep = (uintptr_t)d_ws;
  auto carve = [&](size_t bytes) {
    basep = (basep + 255) & ~(uintptr_t)255;
    void* r = (void*)basep;
    basep += bytes;
    return r;
  };
  float* h    = (float*)carve((size_t)P_ * D_ * 4);
  float* x    = (float*)carve((size_t)P_ * D_ * 4);   // reused: x / ao / x2 / delta
  float* qkvb = (float*)carve((size_t)P_ * 3 * D_ * 4);
  float* ff   = (float*)carve((size_t)P_ * DFF_ * 4);
  int* node   = (int*)carve(P_ * 4);
  int* order  = (int*)carve(P_ * 4);
  int* offs   = (int*)carve(NN_ * 4);
  int* cnts   = (int*)carve(NN_ * 4);

  const int GX = P_ / 32;  // 80 packet-tiles

  encode_kernel<<<P_, 256, 0, stream>>>(query_keys, writer_keys, key_proj_w, key_proj_b,
                                        class_embed, role_embed, start_node_embed,
                                        input_ln_g, input_ln_b, query_start_nodes,
                                        writer_labels, writer_start_nodes, h, node);

  for (int hop = 0; hop < HOPS_; ++hop) {
    sort_kernel<<<1, 256, 0, stream>>>(node, order, offs, cnts);
    ln_affine<<<P_, 256, 0, stream>>>(h, ln1_g, ln1_b, node, x);
    glin<256, 768, 0, 0, 1><<<dim3(GX, 3, NN_), 256, 0, stream>>>(x, wqkv, bqkv, qkvb,
                                                                  order, offs, cnts);
    attn_kernel<<<dim3(GX, NH_), 256, 0, stream>>>(qkvb, node, order, offs, cnts,
                                                   x /*ao*/);
    glin<256, 256, 0, 1, 1><<<dim3(GX, 1, NN_), 256, 0, stream>>>(x, wo, bo, h,
                                                                  order, offs, cnts);
    ln_affine<<<P_, 256, 0, stream>>>(h, ln2_g, ln2_b, node, x);
    glin<256, 1024, 1, 0, 1><<<dim3(GX, 4, NN_), 256, 0, stream>>>(x, w_fc1, b_fc1, ff,
                                                                   order, offs, cnts);
    glin<1024, 256, 0, 1, 1><<<dim3(GX, 1, NN_), 256, 0, stream>>>(ff, w_fc2, b_fc2, h,
                                                                   order, offs, cnts);
    glin<256, 256, 0, 0, 0><<<dim3(GX, 1, 1), 256, 0, stream>>>(h, delta_w, delta_b,
                                                                x /*delta*/, nullptr,
                                                                nullptr, nullptr);
    route_kernel<<<P_, 256, 0, stream>>>(h, dir_w, dir_b, address_table, mag_w, mag_b,
                                         x, node);
  }

  out_kernel<<<P_, 256, 0, stream>>>(h, out_w, out_b, (float*)d_out);
}

// Round 3
// 1349.417 us; speedup vs baseline: 1.9481x; 1.5053x over previous
//
#include <hip/hip_runtime.h>
#include <math.h>

// Problem constants
#define B_    512
#define W_    4
#define KD_   64
#define NC_   32
#define D_    256
#define NN_   16
#define NH_   8
#define AD_   32
#define HOPS_ 4
#define DH_   32
#define DFF_  1024
#define P_    2560
#define BW_   2048   // B*W

#define INV_SQRT_DH 0.17677669529663687f  // 1/sqrt(32)

// ---------------- block-wide sum over 256 threads ----------------
__device__ __forceinline__ float block_sum256(float v, float* red) {
#pragma unroll
  for (int off = 32; off > 0; off >>= 1) v += __shfl_xor(v, off, 64);
  int wid = threadIdx.x >> 6;
  if ((threadIdx.x & 63) == 0) red[wid] = v;
  __syncthreads();
  float s = red[0] + red[1] + red[2] + red[3];
  __syncthreads();
  return s;
}

__device__ __forceinline__ float gelu_tanh(float v) {
  float u = 0.7978845608028654f * (v + 0.044715f * v * v * v);
  return 0.5f * v * (1.0f + tanhf(u));
}

// ---------------- encode writers + queries -> h, node ----------------
__global__ __launch_bounds__(256) void encode_kernel(
    const float* __restrict__ query_keys, const float* __restrict__ writer_keys,
    const float* __restrict__ kpw, const float* __restrict__ kpb,
    const float* __restrict__ ce, const float* __restrict__ re,
    const float* __restrict__ sne, const float* __restrict__ ilg,
    const float* __restrict__ ilb, const int* __restrict__ qsn,
    const int* __restrict__ wl, const int* __restrict__ wsn,
    float* __restrict__ h, int* __restrict__ node) {
  int p = blockIdx.x, t = threadIdx.x;
  __shared__ float fk[KD_];
  __shared__ float red[4];
  const float* key;
  int lab = -1, sn, role;
  if (p < BW_) { key = writer_keys + (size_t)p * KD_; lab = wl[p]; sn = wsn[p]; role = 0; }
  else { int b = p - BW_; key = query_keys + (size_t)b * KD_; sn = qsn[b]; role = 1; }
  if (t < KD_) fk[t] = key[t];
  __syncthreads();

  float acc = kpb[t] + sne[sn * D_ + t] + re[role * D_ + t];
  if (lab >= 0) acc += ce[lab * D_ + t];
#pragma unroll 8
  for (int i = 0; i < KD_; i++) acc += fk[i] * kpw[i * D_ + t];

  float mean = block_sum256(acc, red) * (1.0f / D_);
  float d = acc - mean;
  float var = block_sum256(d * d, red) * (1.0f / D_);
  float xn = d * (1.0f / sqrtf(var + 1e-5f));

  float sw = 0.0f;
  if (t < KD_) sw = fk[t];
  else if (lab >= 0 && t < KD_ + NC_) sw = (t - KD_ == lab) ? 1.0f : 0.0f;

  h[(size_t)p * D_ + t] = xn * ilg[t] + ilb[t] + sw;
  if (t == 0) node[p] = sn;
}

// ---------------- group packets by node ----------------
__global__ __launch_bounds__(256) void sort_kernel(const int* __restrict__ node,
                                                   int* __restrict__ order,
                                                   int* __restrict__ offs,
                                                   int* __restrict__ cnts) {
  __shared__ int c[NN_], o[NN_], cur[NN_];
  int t = threadIdx.x;
  if (t < NN_) c[t] = 0;
  __syncthreads();
  for (int p = t; p < P_; p += 256) atomicAdd(&c[node[p]], 1);
  __syncthreads();
  if (t == 0) {
    int s = 0;
    for (int n = 0; n < NN_; n++) { o[n] = s; cur[n] = s; s += c[n]; }
  }
  __syncthreads();
  if (t < NN_) { cnts[t] = c[t]; offs[t] = o[t]; }
  for (int p = t; p < P_; p += 256) {
    int r = atomicAdd(&cur[node[p]], 1);
    order[r] = p;
  }
}

// ---------------- LN with per-node affine ----------------
__global__ __launch_bounds__(256) void ln_affine(const float* __restrict__ h,
                                                 const float* __restrict__ g,
                                                 const float* __restrict__ b,
                                                 const int* __restrict__ node,
                                                 float* __restrict__ x) {
  int p = blockIdx.x, t = threadIdx.x;
  __shared__ float red[4];
  int n = node[p];
  float v = h[(size_t)p * D_ + t];
  float mean = block_sum256(v, red) * (1.0f / D_);
  float d = v - mean;
  float var = block_sum256(d * d, red) * (1.0f / D_);
  float xn = d * (1.0f / sqrtf(var + 1e-5f));
  x[(size_t)p * D_ + t] = xn * g[n * D_ + t] + b[n * D_ + t];
}

// ---------------- grouped (per-node or dense) linear, v2 -------------------
// Double-buffered tiled GEMM: block tile MT=64 x JT=64, 256 threads, 4x4
// register tile per thread, KC=32 K-chunks, one barrier per chunk.
// out[p, jbase:jbase+64] = act( x[p,:] @ W[n] + bias[n] )   (+= when RESID)
template <int DIN, int DOUT, int ACT, int RESID, int PER_NODE>
__global__ __launch_bounds__(256) void glin(const float* __restrict__ x,
                                            const float* __restrict__ W,
                                            const float* __restrict__ bias,
                                            float* __restrict__ out,
                                            const int* __restrict__ order,
                                            const int* __restrict__ offs,
                                            const int* __restrict__ cnts) {
  constexpr int MT = 64, JT = 64, KC = 32, ST = 68;  // ST: pad to keep b128 align, avoid conflicts
  constexpr int NCH = DIN / KC;
  int n = PER_NODE ? blockIdx.z : 0;
  int m = PER_NODE ? cnts[n] : P_;
  int m0 = blockIdx.x * MT;
  if (m0 >= m) return;
  int base = PER_NODE ? offs[n] : 0;
  int jbase = blockIdx.y * JT;

  __shared__ float xs[2][KC][ST];  // transposed: xs[buf][k][mrow]
  __shared__ float ws[2][KC][ST];  // ws[buf][k][jcol]
  __shared__ int pid[MT];

  int tid = threadIdx.x;
  if (tid < MT) {
    int idx = m0 + tid;
    pid[tid] = (idx < m) ? (PER_NODE ? order[base + idx] : idx) : -1;
  }
  __syncthreads();

  const float* Wn = W + (size_t)n * DIN * DOUT + jbase;

  // x slot s (0..511): mrow = s>>3, kq = s&7  (8 float4 per row of 32 k)
  // w slot s (0..511): k = s>>4,   jq = s&15 (16 float4 per k-row of 64 j)
  auto loadx = [&](int kc, int s) -> float4 {
    int mr = s >> 3, kq = s & 7;
    int pp = pid[mr];
    if (pp < 0) return make_float4(0.f, 0.f, 0.f, 0.f);
    return *(const float4*)&x[(size_t)pp * DIN + kc + kq * 4];
  };
  auto loadw = [&](int kc, int s) -> float4 {
    int k = s >> 4, jq = s & 15;
    return *(const float4*)&Wn[(size_t)(kc + k) * DOUT + jq * 4];
  };
  auto storex = [&](int buf, int s, float4 v) {
    int mr = s >> 3, k0 = (s & 7) * 4;
    xs[buf][k0 + 0][mr] = v.x;
    xs[buf][k0 + 1][mr] = v.y;
    xs[buf][k0 + 2][mr] = v.z;
    xs[buf][k0 + 3][mr] = v.w;
  };
  auto storew = [&](int buf, int s, float4 v) {
    int k = s >> 4, jq = s & 15;
    *(float4*)&ws[buf][k][jq * 4] = v;
  };

  // prologue: stage chunk 0
  {
    float4 a0 = loadx(0, tid), a1 = loadx(0, tid + 256);
    float4 b0 = loadw(0, tid), b1 = loadw(0, tid + 256);
    storex(0, tid, a0); storex(0, tid + 256, a1);
    storew(0, tid, b0); storew(0, tid + 256, b1);
  }
  __syncthreads();

  int rc4 = (tid >> 4) * 4;  // my 4 rows
  int jc4 = (tid & 15) * 4;  // my 4 cols
  float acc[4][4] = {{0.f}};

  for (int c = 0; c < NCH; c++) {
    int cur = c & 1, nxt = cur ^ 1;
    bool hasnext = (c + 1 < NCH);
    float4 a0, a1, b0, b1;
    if (hasnext) {
      int kc = (c + 1) * KC;
      a0 = loadx(kc, tid); a1 = loadx(kc, tid + 256);
      b0 = loadw(kc, tid); b1 = loadw(kc, tid + 256);
    }
#pragma unroll 8
    for (int k = 0; k < KC; k++) {
      float4 a = *(const float4*)&xs[cur][k][rc4];  // 16-lane broadcast, conflict-free
      float4 b = *(const float4*)&ws[cur][k][jc4];  // 2-way = free
      acc[0][0] += a.x * b.x; acc[0][1] += a.x * b.y; acc[0][2] += a.x * b.z; acc[0][3] += a.x * b.w;
      acc[1][0] += a.y * b.x; acc[1][1] += a.y * b.y; acc[1][2] += a.y * b.z; acc[1][3] += a.y * b.w;
      acc[2][0] += a.z * b.x; acc[2][1] += a.z * b.y; acc[2][2] += a.z * b.z; acc[2][3] += a.z * b.w;
      acc[3][0] += a.w * b.x; acc[3][1] += a.w * b.y; acc[3][2] += a.w * b.z; acc[3][3] += a.w * b.w;
    }
    if (hasnext) {
      storex(nxt, tid, a0); storex(nxt, tid + 256, a1);
      storew(nxt, tid, b0); storew(nxt, tid + 256, b1);
    }
    __syncthreads();
  }

  float4 bb = *(const float4*)&bias[n * DOUT + jbase + jc4];
#pragma unroll
  for (int r = 0; r < 4; r++) {
    int pp = pid[rc4 + r];
    if (pp < 0) continue;
    float4 v;
    v.x = acc[r][0] + bb.x;
    v.y = acc[r][1] + bb.y;
    v.z = acc[r][2] + bb.z;
    v.w = acc[r][3] + bb.w;
    if (ACT == 1) {
      v.x = gelu_tanh(v.x); v.y = gelu_tanh(v.y);
      v.z = gelu_tanh(v.z); v.w = gelu_tanh(v.w);
    }
    float* op = &out[(size_t)pp * DOUT + jbase + jc4];
    if (RESID) {
      float4 old = *(const float4*)op;
      v.x += old.x; v.y += old.y; v.z += old.z; v.w += old.w;
    }
    *(float4*)op = v;
  }
}

// ---------------- same-node attention, flash-style over sorted order --------
// grid (P/32, NH). Block handles 32 sorted q-rows for one head.
// Groups are contiguous in sorted order, so the same-node mask is a range
// test on the sorted key index. Online softmax per row (8 lanes/row).
#define ATS 36  // padded LDS stride (floats): multiple of 4 (float4 align), !=32 (banks)
__global__ __launch_bounds__(256) void attn_kernel(const float* __restrict__ qkv,
                                                   const int* __restrict__ node,
                                                   const int* __restrict__ order,
                                                   const int* __restrict__ offs,
                                                   const int* __restrict__ cnts,
                                                   float* __restrict__ ao) {
  __shared__ float qs[32 * ATS];   // Q row-major [r][d]
  __shared__ float kts[32 * ATS];  // K transposed [d][j]
  __shared__ float vs[32 * ATS];   // V row-major [j][d]
  __shared__ float ps[32 * ATS];   // P row-major [r][j] (wave-coherent use)
  __shared__ int prow[32], glo[32], ghi[32];

  int t = threadIdx.x;
  int r = t >> 3;          // my q-row (and my staging key-row)
  int j4 = (t & 7) * 4;    // my 4 score-cols == my 4 output dims
  int r0 = blockIdx.x * 32;
  int hd = blockIdx.y;

  if (t < 32) {
    int sr = r0 + t;
    int pp = order[sr];
    prow[t] = pp;
    int n = node[pp];
    glo[t] = offs[n];
    ghi[t] = offs[n] + cnts[n];
  }
  __syncthreads();

  {  // load Q tile (wave-coherent with its consumers: row r lives in 8 lanes of one wave)
    const float* qp = &qkv[(size_t)prow[r] * 768 + hd * 32 + j4];
    float4 q4 = *(const float4*)qp;
    q4.x *= INV_SQRT_DH; q4.y *= INV_SQRT_DH; q4.z *= INV_SQRT_DH; q4.w *= INV_SQRT_DH;
    *(float4*)&qs[r * ATS + j4] = q4;
  }

  int lo = glo[0];          // sorted ascending => row 0 has min group start
  int hi = ghi[31];         // row 31 has max group end
  int myglo = glo[r], myghi = ghi[r];

  float4 o4 = {0.f, 0.f, 0.f, 0.f};
  float mrow = -1e30f, lrow = 0.f;

  for (int kt = lo; kt < hi; kt += 32) {
    // stage: this thread loads key-row (kt+r), dims j4..j4+3
    int sj = kt + r;
    float4 k4 = {0.f, 0.f, 0.f, 0.f}, v4 = {0.f, 0.f, 0.f, 0.f};
    if (sj < hi) {
      const float* kp = &qkv[(size_t)order[sj] * 768 + 256 + hd * 32 + j4];
      k4 = *(const float4*)kp;
      v4 = *(const float4*)(kp + 256);
    }
    __syncthreads();  // previous tile's kts/vs reads complete
    kts[(j4 + 0) * ATS + r] = k4.x;
    kts[(j4 + 1) * ATS + r] = k4.y;
    kts[(j4 + 2) * ATS + r] = k4.z;
    kts[(j4 + 3) * ATS + r] = k4.w;
    *(float4*)&vs[r * ATS + j4] = v4;
    __syncthreads();

    // scores: 4 cols per thread, dot over 32 dims
    float s0 = 0.f, s1 = 0.f, s2 = 0.f, s3 = 0.f;
#pragma unroll 8
    for (int d = 0; d < 32; d++) {
      float qv = qs[r * ATS + d];                     // broadcast within row-group
      float4 kv = *(const float4*)&kts[d * ATS + j4]; // conflict-free (stride 36)
      s0 += qv * kv.x; s1 += qv * kv.y; s2 += qv * kv.z; s3 += qv * kv.w;
    }
    // same-node mask via sorted range
    int c0 = kt + j4;
    if (c0 + 0 < myglo || c0 + 0 >= myghi) s0 = -1e30f;
    if (c0 + 1 < myglo || c0 + 1 >= myghi) s1 = -1e30f;
    if (c0 + 2 < myglo || c0 + 2 >= myghi) s2 = -1e30f;
    if (c0 + 3 < myglo || c0 + 3 >= myghi) s3 = -1e30f;

    // online softmax (per row across its 8 lanes)
    float mx = fmaxf(fmaxf(s0, s1), fmaxf(s2, s3));
#pragma unroll
    for (int off = 4; off > 0; off >>= 1) mx = fmaxf(mx, __shfl_xor(mx, off, 8));
    float mnew = fmaxf(mrow, mx);
    float alpha = __expf(mrow - mnew);  // exp(0)=1 harmless pre-first-valid (zeroed later)
    float p0 = __expf(s0 - mnew), p1 = __expf(s1 - mnew);
    float p2 = __expf(s2 - mnew), p3 = __expf(s3 - mnew);
    float ls = p0 + p1 + p2 + p3;
#pragma unroll
    for (int off = 4; off > 0; off >>= 1) ls += __shfl_xor(ls, off, 8);
    lrow = lrow * alpha + ls;
    mrow = mnew;
    o4.x *= alpha; o4.y *= alpha; o4.z *= alpha; o4.w *= alpha;

    // P -> LDS (row written & read by the same 8 lanes' wave: no barrier needed)
    *(float4*)&ps[r * ATS + j4] = make_float4(p0, p1, p2, p3);
#pragma unroll 8
    for (int j = 0; j < 32; j++) {
      float pj = ps[r * ATS + j];
      float4 vv = *(const float4*)&vs[j * ATS + j4];
      o4.x += pj * vv.x; o4.y += pj * vv.y; o4.z += pj * vv.z; o4.w += pj * vv.w;
    }
  }

  float inv = 1.f / lrow;
  o4.x *= inv; o4.y *= inv; o4.z *= inv; o4.w *= inv;
  *(float4*)&ao[(size_t)prow[r] * D_ + hd * 32 + j4] = o4;
}

// ---------------- routing: dir scores -> argmax node; h += delta*sigmoid(mag) ----
__global__ __launch_bounds__(256) void route_kernel(float* __restrict__ h,
                                                    const float* __restrict__ dir_w,
                                                    const float* __restrict__ dir_b,
                                                    const float* __restrict__ at,
                                                    const float* __restrict__ mag_w,
                                                    const float* __restrict__ mag_b,
                                                    const float* __restrict__ delta,
                                                    int* __restrict__ node) {
  int p = blockIdx.x, t = threadIdx.x;
  __shared__ float hs[D_];
  __shared__ float dpart[8][AD_];
  __shared__ float dirs[AD_];
  __shared__ float scs[NN_];
  __shared__ float red[4];
  float hv = h[(size_t)p * D_ + t];
  hs[t] = hv;
  __syncthreads();

  // direction[:AD] only (the rest is never used by the reference)
  int j = t & 31, seg = t >> 5;
  float part = 0.0f;
#pragma unroll 8
  for (int i = 0; i < 32; i++) {
    int ii = seg * 32 + i;
    part += hs[ii] * dir_w[ii * D_ + j];
  }
  dpart[seg][j] = part;
  __syncthreads();
  if (t < AD_) {
    float s = dir_b[t];
#pragma unroll
    for (int g = 0; g < 8; g++) s += dpart[g][t];
    dirs[t] = s;
  }
  __syncthreads();
  if (t < NN_) {
    float s = 0.0f;
#pragma unroll
    for (int a = 0; a < AD_; a++) s += dirs[a] * at[t * AD_ + a];
    scs[t] = s;
  }
  __syncthreads();
  if (t == 0) {
    float best = scs[0];
    int arg = 0;
    for (int nn = 1; nn < NN_; nn++)
      if (scs[nn] > best) { best = scs[nn]; arg = nn; }  // first-max like jnp.argmax
    node[p] = arg;
  }
  // gated delta
  float mag = block_sum256(hv * mag_w[t], red) + mag_b[0];
  float sig = 1.0f / (1.0f + __expf(-mag));
  h[(size_t)p * D_ + t] = hv + delta[(size_t)p * D_ + t] * sig;
}

// ---------------- final logits ----------------
__global__ __launch_bounds__(256) void out_kernel(const float* __restrict__ h,
                                                  const float* __restrict__ ow,
                                                  const float* __restrict__ ob,
                                                  float* __restrict__ out) {
  int p = blockIdx.x, t = threadIdx.x;
  __shared__ float hs[D_];
  __shared__ float part[8][NC_];
  hs[t] = h[(size_t)p * D_ + t];
  __syncthreads();
  int j = t & 31, seg = t >> 5;
  float s = 0.0f;
#pragma unroll 8
  for (int i = 0; i < 32; i++) {
    int ii = seg * 32 + i;
    s += hs[ii] * ow[ii * NC_ + j];
  }
  part[seg][j] = s;
  __syncthreads();
  if (t < NC_) {
    float r = ob[t];
#pragma unroll
    for (int g = 0; g < 8; g++) r += part[g][t];
    out[(size_t)p * NC_ + t] = r;
  }
}

extern "C" void kernel_launch(void* const* d_in, const int* in_sizes, int n_in,
                              void* d_out, int out_size, void* d_ws, size_t ws_size,
                              hipStream_t stream) {
  (void)in_sizes; (void)n_in; (void)out_size; (void)ws_size;
  const float* query_keys       = (const float*)d_in[0];
  const float* writer_keys      = (const float*)d_in[1];
  const float* key_proj_w       = (const float*)d_in[2];
  const float* key_proj_b       = (const float*)d_in[3];
  const float* class_embed      = (const float*)d_in[4];
  const float* role_embed       = (const float*)d_in[5];
  const float* start_node_embed = (const float*)d_in[6];
  const float* input_ln_g       = (const float*)d_in[7];
  const float* input_ln_b       = (const float*)d_in[8];
  const float* ln1_g            = (const float*)d_in[9];
  const float* ln1_b            = (const float*)d_in[10];
  const float* wqkv             = (const float*)d_in[11];
  const float* bqkv             = (const float*)d_in[12];
  const float* wo               = (const float*)d_in[13];
  const float* bo               = (const float*)d_in[14];
  const float* ln2_g            = (const float*)d_in[15];
  const float* ln2_b            = (const float*)d_in[16];
  const float* w_fc1            = (const float*)d_in[17];
  const float* b_fc1            = (const float*)d_in[18];
  const float* w_fc2            = (const float*)d_in[19];
  const float* b_fc2            = (const float*)d_in[20];
  const float* delta_w          = (const float*)d_in[21];
  const float* delta_b          = (const float*)d_in[22];
  const float* dir_w            = (const float*)d_in[23];
  const float* dir_b            = (const float*)d_in[24];
  const float* mag_w            = (const float*)d_in[25];
  const float* mag_b            = (const float*)d_in[26];
  const float* out_w            = (const float*)d_in[27];
  const float* out_b            = (const float*)d_in[28];
  const float* address_table    = (const float*)d_in[29];
  const int* query_start_nodes  = (const int*)d_in[30];
  const int* writer_labels      = (const int*)d_in[31];
  const int* writer_start_nodes = (const int*)d_in[32];

  uintptr_t basep = (uintptr_t)d_ws;
  auto carve = [&](size_t bytes) {
    basep = (basep + 255) & ~(uintptr_t)255;
    void* r = (void*)basep;
    basep += bytes;
    return r;
  };
  float* h    = (float*)carve((size_t)P_ * D_ * 4);
  float* x    = (float*)carve((size_t)P_ * D_ * 4);   // reused: x / ao / x2 / delta
  float* qkvb = (float*)carve((size_t)P_ * 3 * D_ * 4);
  float* ff   = (float*)carve((size_t)P_ * DFF_ * 4);
  int* node   = (int*)carve(P_ * 4);
  int* order  = (int*)carve(P_ * 4);
  int* offs   = (int*)carve(NN_ * 4);
  int* cnts   = (int*)carve(NN_ * 4);

  const int GM = P_ / 64;  // 40 M-chunks (worst case: one node owns all packets)

  encode_kernel<<<P_, 256, 0, stream>>>(query_keys, writer_keys, key_proj_w, key_proj_b,
                                        class_embed, role_embed, start_node_embed,
                                        input_ln_g, input_ln_b, query_start_nodes,
                                        writer_labels, writer_start_nodes, h, node);

  for (int hop = 0; hop < HOPS_; ++hop) {
    sort_kernel<<<1, 256, 0, stream>>>(node, order, offs, cnts);
    ln_affine<<<P_, 256, 0, stream>>>(h, ln1_g, ln1_b, node, x);
    glin<256, 768, 0, 0, 1><<<dim3(GM, 12, NN_), 256, 0, stream>>>(x, wqkv, bqkv, qkvb,
                                                                   order, offs, cnts);
    attn_kernel<<<dim3(P_ / 32, NH_), 256, 0, stream>>>(qkvb, node, order, offs, cnts,
                                                        x /*ao*/);
    glin<256, 256, 0, 1, 1><<<dim3(GM, 4, NN_), 256, 0, stream>>>(x, wo, bo, h,
                                                                  order, offs, cnts);
    ln_affine<<<P_, 256, 0, stream>>>(h, ln2_g, ln2_b, node, x);
    glin<256, 1024, 1, 0, 1><<<dim3(GM, 16, NN_), 256, 0, stream>>>(x, w_fc1, b_fc1, ff,
                                                                    order, offs, cnts);
    glin<1024, 256, 0, 1, 1><<<dim3(GM, 4, NN_), 256, 0, stream>>>(ff, w_fc2, b_fc2, h,
                                                                   order, offs, cnts);
    glin<256, 256, 0, 0, 0><<<dim3(GM, 4, 1), 256, 0, stream>>>(h, delta_w, delta_b,
                                                                x /*delta*/, nullptr,
                                                                nullptr, nullptr);
    route_kernel<<<P_, 256, 0, stream>>>(h, dir_w, dir_b, address_table, mag_w, mag_b,
                                         x, node);
  }

  out_kernel<<<P_, 256, 0, stream>>>(h, out_w, out_b, (float*)d_out);
}